// Round 2
// baseline (325.632 us; speedup 1.0000x reference)
//
#include <hip/hip_runtime.h>

#define NN 64
#define IND 256
#define NH 8
#define OD 32

__device__ __forceinline__ unsigned f2bf(float f) {
  unsigned u = __float_as_uint(f);
  return (u + (((u >> 16) & 1u) + 0x7fffu)) >> 16;  // RNE
}
__device__ __forceinline__ float bflo(unsigned u) { return __uint_as_float(u << 16); }
__device__ __forceinline__ float bfhi(unsigned u) { return __uint_as_float(u & 0xffff0000u); }

// V[h][k] = sum_d W[k, h*32+d] * Watt[h, d]   (8 x 256)
__global__ __launch_bounds__(256) void precompute_v(
    const float* __restrict__ W, const float* __restrict__ Watt, float* __restrict__ V) {
  int tid = blockIdx.x * 256 + threadIdx.x;
  if (tid >= IND * NH) return;
  int h = tid >> 8, k = tid & 255;
  float acc = 0.f;
#pragma unroll
  for (int d = 0; d < OD; ++d) acc += W[k * 256 + h * OD + d] * Watt[h * OD + d];
  V[h * 256 + k] = acc;
}

// LDS layout (bytes):
//  [0,     33792)  s bf16 [64][264] (row = 132 words -> 4-bank shift/row)
//                  overlay post-barrier-1: yp float [32][260]  (33280 B)
//  [33792, 38016)  v bf16 [8][264]  (4224 B)
//                  overlay post-barrier-1: alpha float [64][8] (2048 B)
//                  overlay post-barrier-2: pp float [4][256]   (4096 B)
//  [38016, 40320)  e float [64][9]  (2304 B; 9-stride kills 8-way conflict)
#define V_OFF 33792
#define E_OFF (V_OFF + 4224)
#define SMEM_BYTES (E_OFF + 2304)

__global__ __launch_bounds__(256, 4) void gat_fused(
    const float* __restrict__ Xi, const float* __restrict__ Xj,
    const float* __restrict__ W, const float* __restrict__ V,
    float* __restrict__ out) {
  __shared__ __align__(16) unsigned char smem[SMEM_BYTES];
  unsigned* s_pk = (unsigned*)smem;
  unsigned* v_pk = (unsigned*)(smem + V_OFF);
  float* e_f = (float*)(smem + E_OFF);
  float* alpha_f = (float*)(smem + V_OFF);  // overlay: valid after barrier 1 (v dead)
  float* pp_f = (float*)(smem + V_OFF);     // overlay: valid after barrier 2 (alpha dead)
  float* yp_f = (float*)smem;               // overlay: valid after barrier 1 (s dead)

  const int t = threadIdx.x;
  const int b = blockIdx.x;
  const int w = t >> 6, l = t & 63;
  const int g = l >> 3, h = l & 7;

  // wave w owns rows [16w, 16w+16) end-to-end
  const float4* Xi4 = (const float4*)Xi + (size_t)b * (NN * IND / 4) + w * 1024;
  const float4* Xj4 = (const float4*)Xj + (size_t)b * (NN * IND / 4) + w * 1024;

  // stage V into LDS as bf16 [8][264] — redundantly per wave (identical values),
  // keeps Phase B wave-local (no barrier before B).
  {
    const float4* V4 = (const float4*)V;
#pragma unroll
    for (int r = 0; r < 8; ++r) {
      float4 vv = V4[r * 64 + l];
      unsigned p0 = f2bf(vv.x) | (f2bf(vv.y) << 16);
      unsigned p1 = f2bf(vv.z) | (f2bf(vv.w) << 16);
      *(uint2*)(v_pk + r * 132 + 2 * l) = make_uint2(p0, p1);
    }
  }

  // Phase A: xj persistent in regs (64 VGPR); xi streamed in 2 chunks of 8
  // (32 VGPR transient) so total stays under the 128-VGPR / 4-wave cap — no spill.
  float4 xj[16];
#pragma unroll
  for (int i = 0; i < 16; ++i) xj[i] = Xj4[i * 64 + l];
#pragma unroll
  for (int c = 0; c < 2; ++c) {
    float4 xi[8];
#pragma unroll
    for (int i = 0; i < 8; ++i) xi[i] = Xi4[(c * 8 + i) * 64 + l];
#pragma unroll
    for (int i = 0; i < 8; ++i) {
      int r = c * 8 + i;
      float4 a = xj[r], ci = xi[i];
      unsigned p0 = f2bf(a.x + ci.x) | (f2bf(a.y + ci.y) << 16);
      unsigned p1 = f2bf(a.z + ci.z) | (f2bf(a.w + ci.w) << 16);
      *(uint2*)(s_pk + (w * 16 + r) * 132 + l * 2) = make_uint2(p0, p1);
    }
  }

  // Phase B: e[n][h] = leakyrelu(s[n,:].V[h,:]) for own rows only — intra-wave
  // LDS dependency, no barrier. srow rows at 4-bank shift, vrow broadcast: conflict-free.
  float er[2];
#pragma unroll
  for (int pp = 0; pp < 2; ++pp) {
    int n = w * 16 + g + 8 * pp;
    const uint4* srow = (const uint4*)(s_pk + n * 132);
    const uint4* vrow = (const uint4*)(v_pk + h * 132);
    float acc = 0.f;
#pragma unroll 8
    for (int kk = 0; kk < 32; ++kk) {
      uint4 sp = srow[kk];
      uint4 vp = vrow[kk];
      acc += bflo(sp.x) * bflo(vp.x) + bfhi(sp.x) * bfhi(vp.x)
           + bflo(sp.y) * bflo(vp.y) + bfhi(sp.y) * bfhi(vp.y)
           + bflo(sp.z) * bflo(vp.z) + bfhi(sp.z) * bfhi(vp.z)
           + bflo(sp.w) * bflo(vp.w) + bfhi(sp.w) * bfhi(vp.w);
    }
    er[pp] = acc >= 0.f ? acc : 0.2f * acc;
    e_f[n * 9 + h] = er[pp];
  }
  __syncthreads();  // barrier 1: e complete; s and v globally dead past this point

  // softmax over n per h: redundantly per wave (butterfly over the 8 lane-groups).
  // e stride 9 -> reads are <=2-way bank aliased (free), was 8-way at stride 8.
  float m = -3.4e38f;
#pragma unroll
  for (int q = 0; q < 8; ++q) m = fmaxf(m, e_f[(g * 8 + q) * 9 + h]);
  m = fmaxf(m, __shfl_xor(m, 8, 64));
  m = fmaxf(m, __shfl_xor(m, 16, 64));
  m = fmaxf(m, __shfl_xor(m, 32, 64));
  float ssum = 0.f;
#pragma unroll
  for (int q = 0; q < 8; ++q) ssum += __expf(e_f[(g * 8 + q) * 9 + h] - m);
  ssum += __shfl_xor(ssum, 8, 64);
  ssum += __shfl_xor(ssum, 16, 64);
  ssum += __shfl_xor(ssum, 32, 64);
  float rinv = 1.f / ssum;

  // alpha for own rows (e still in regs); consumed only by this wave's Phase C.
#pragma unroll
  for (int pp = 0; pp < 2; ++pp) {
    int n = w * 16 + g + 8 * pp;
    alpha_f[n * 8 + h] = __expf(er[pp] - m) * rinv;
  }

  // Phase C: y partials from register-held xj; alpha reads are wave-local
  // broadcasts — no barrier needed.
  float4 acc4[8];
#pragma unroll
  for (int hh = 0; hh < 8; ++hh) acc4[hh] = make_float4(0.f, 0.f, 0.f, 0.f);
#pragma unroll
  for (int i = 0; i < 16; ++i) {
    int n = w * 16 + i;
    float4 a0 = *(const float4*)(alpha_f + n * 8);
    float4 a1 = *(const float4*)(alpha_f + n * 8 + 4);
    float al[8] = {a0.x, a0.y, a0.z, a0.w, a1.x, a1.y, a1.z, a1.w};
    float4 x = xj[i];
#pragma unroll
    for (int hh = 0; hh < 8; ++hh) {
      acc4[hh].x += al[hh] * x.x;
      acc4[hh].y += al[hh] * x.y;
      acc4[hh].z += al[hh] * x.z;
      acc4[hh].w += al[hh] * x.w;
    }
  }
#pragma unroll
  for (int hh = 0; hh < 8; ++hh)
    *(float4*)(yp_f + (w * 8 + hh) * 260 + 4 * l) = acc4[hh];  // stride 260: epilogue reads conflict-free
  __syncthreads();  // barrier 2: yp complete

  // Epilogue: out[c] = elu(y[h(c)] . W[:,c]); k split across waves, float4 W loads,
  // 4-wave partials reduced via LDS.
  {
    const float* ypb = yp_f + g * 260;          // g == (4l)>>5: head of columns 4l..4l+3
    const float4* W4 = (const float4*)W;        // W4[k*64 + l] = W[k][4l..4l+3]
    float4 acc = make_float4(0.f, 0.f, 0.f, 0.f);
    int k0 = w * 64;
#pragma unroll 8
    for (int kk = 0; kk < 64; ++kk) {
      int k = k0 + kk;
      float yv = ypb[k] + ypb[2080 + k] + ypb[4160 + k] + ypb[6240 + k];
      float4 wv = W4[k * 64 + l];
      acc.x += yv * wv.x;
      acc.y += yv * wv.y;
      acc.z += yv * wv.z;
      acc.w += yv * wv.w;
    }
    *(float4*)(pp_f + w * 256 + 4 * l) = acc;
  }
  __syncthreads();  // barrier 3: partials complete

  {
    float s = pp_f[t] + pp_f[256 + t] + pp_f[512 + t] + pp_f[768 + t];
    out[(size_t)b * 256 + t] = s > 0.f ? s : (__expf(s) - 1.f);
  }
}

extern "C" void kernel_launch(void* const* d_in, const int* in_sizes, int n_in,
                              void* d_out, int out_size, void* d_ws, size_t ws_size,
                              hipStream_t stream) {
  const float* Xi = (const float*)d_in[0];
  const float* Xj = (const float*)d_in[1];
  const float* W = (const float*)d_in[2];
  const float* Watt = (const float*)d_in[3];
  float* out = (float*)d_out;
  float* V = (float*)d_ws;  // 2048 floats
  int B = in_sizes[0] / (NN * IND);
  precompute_v<<<(IND * NH + 255) / 256, 256, 0, stream>>>(W, Watt, V);
  gat_fused<<<B, 256, 0, stream>>>(Xi, Xj, W, V, out);
}

// Round 3
// 293.202 us; speedup vs baseline: 1.1106x; 1.1106x over previous
//
#include <hip/hip_runtime.h>

#define NN 64
#define IND 256
#define NH 8
#define OD 32

__device__ __forceinline__ unsigned f2bf(float f) {
  unsigned u = __float_as_uint(f);
  return (u + (((u >> 16) & 1u) + 0x7fffu)) >> 16;  // RNE
}
__device__ __forceinline__ float bflo(unsigned u) { return __uint_as_float(u << 16); }
__device__ __forceinline__ float bfhi(unsigned u) { return __uint_as_float(u & 0xffff0000u); }

// V[h][k] = sum_d W[k, h*32+d] * Watt[h, d]   (8 x 256)
__global__ __launch_bounds__(256) void precompute_v(
    const float* __restrict__ W, const float* __restrict__ Watt, float* __restrict__ V) {
  int tid = blockIdx.x * 256 + threadIdx.x;
  if (tid >= IND * NH) return;
  int h = tid >> 8, k = tid & 255;
  float acc = 0.f;
#pragma unroll
  for (int d = 0; d < OD; ++d) acc += W[k * 256 + h * OD + d] * Watt[h * OD + d];
  V[h * 256 + k] = acc;
}

// LDS layout (bytes):
//  [0,     33792)  s bf16 [64][264] (row = 132 words -> 4-bank shift/row)
//                  overlay post-barrier-1: yp float [32][260]  (33280 B)
//  [33792, 38016)  v bf16 [8][264]  (4224 B)
//                  overlay post-barrier-1: alpha float [64][8] (2048 B)
//                  overlay post-barrier-2: pp float [4][256]   (4096 B)
//  [38016, 40320)  e float [64][9]  (2304 B; 9-stride kills 8-way conflict)
#define V_OFF 33792
#define E_OFF (V_OFF + 4224)
#define SMEM_BYTES (E_OFF + 2304)

// NOTE: no min-waves arg. Measured allocator behavior: (256,3)->84 VGPR,
// (256,4)->64 VGPR (cap ~ 512/(2*arg)) -> guaranteed spill with the 64-reg
// xj payload (WRITE_SIZE 62/122 MB). LDS=40448 already caps occupancy at
// 4 blocks/CU, so plain bounds lets the allocator use the full 128-VGPR
// step spill-free without costing occupancy.
__global__ __launch_bounds__(256) void gat_fused(
    const float* __restrict__ Xi, const float* __restrict__ Xj,
    const float* __restrict__ W, const float* __restrict__ V,
    float* __restrict__ out) {
  __shared__ __align__(16) unsigned char smem[SMEM_BYTES];
  unsigned* s_pk = (unsigned*)smem;
  unsigned* v_pk = (unsigned*)(smem + V_OFF);
  float* e_f = (float*)(smem + E_OFF);
  float* alpha_f = (float*)(smem + V_OFF);  // overlay: valid after barrier 1 (v dead)
  float* pp_f = (float*)(smem + V_OFF);     // overlay: valid after barrier 2 (alpha dead)
  float* yp_f = (float*)smem;               // overlay: valid after barrier 1 (s dead)

  const int t = threadIdx.x;
  const int b = blockIdx.x;
  const int w = t >> 6, l = t & 63;
  const int g = l >> 3, h = l & 7;

  // wave w owns rows [16w, 16w+16) end-to-end
  const float4* Xi4 = (const float4*)Xi + (size_t)b * (NN * IND / 4) + w * 1024;
  const float4* Xj4 = (const float4*)Xj + (size_t)b * (NN * IND / 4) + w * 1024;

  // stage V into LDS as bf16 [8][264] — redundantly per wave (identical values),
  // keeps Phase B wave-local (no barrier before B).
  {
    const float4* V4 = (const float4*)V;
#pragma unroll
    for (int r = 0; r < 8; ++r) {
      float4 vv = V4[r * 64 + l];
      unsigned p0 = f2bf(vv.x) | (f2bf(vv.y) << 16);
      unsigned p1 = f2bf(vv.z) | (f2bf(vv.w) << 16);
      *(uint2*)(v_pk + r * 132 + 2 * l) = make_uint2(p0, p1);
    }
  }

  // Phase A: xj persistent in regs (64 VGPR); xi streamed in 2 chunks of 8
  // (32 VGPR transient). Live set ~112 <= 128-VGPR occupancy step.
  float4 xj[16];
#pragma unroll
  for (int i = 0; i < 16; ++i) xj[i] = Xj4[i * 64 + l];
#pragma unroll
  for (int c = 0; c < 2; ++c) {
    float4 xi[8];
#pragma unroll
    for (int i = 0; i < 8; ++i) xi[i] = Xi4[(c * 8 + i) * 64 + l];
#pragma unroll
    for (int i = 0; i < 8; ++i) {
      int r = c * 8 + i;
      float4 a = xj[r], ci = xi[i];
      unsigned p0 = f2bf(a.x + ci.x) | (f2bf(a.y + ci.y) << 16);
      unsigned p1 = f2bf(a.z + ci.z) | (f2bf(a.w + ci.w) << 16);
      *(uint2*)(s_pk + (w * 16 + r) * 132 + l * 2) = make_uint2(p0, p1);
    }
  }

  // Phase B: e[n][h] = leakyrelu(s[n,:].V[h,:]) for own rows only — intra-wave
  // LDS dependency, no barrier. srow rows at 4-bank shift, vrow broadcast: conflict-free.
  float er[2];
#pragma unroll
  for (int pp = 0; pp < 2; ++pp) {
    int n = w * 16 + g + 8 * pp;
    const uint4* srow = (const uint4*)(s_pk + n * 132);
    const uint4* vrow = (const uint4*)(v_pk + h * 132);
    float acc = 0.f;
#pragma unroll 8
    for (int kk = 0; kk < 32; ++kk) {
      uint4 sp = srow[kk];
      uint4 vp = vrow[kk];
      acc += bflo(sp.x) * bflo(vp.x) + bfhi(sp.x) * bfhi(vp.x)
           + bflo(sp.y) * bflo(vp.y) + bfhi(sp.y) * bfhi(vp.y)
           + bflo(sp.z) * bflo(vp.z) + bfhi(sp.z) * bfhi(vp.z)
           + bflo(sp.w) * bflo(vp.w) + bfhi(sp.w) * bfhi(vp.w);
    }
    er[pp] = acc >= 0.f ? acc : 0.2f * acc;
    e_f[n * 9 + h] = er[pp];
  }
  __syncthreads();  // barrier 1: e complete; s and v globally dead past this point

  // softmax over n per h: redundantly per wave (butterfly over the 8 lane-groups).
  // e stride 9 -> reads <=2-way bank aliased (free); was 8-way at stride 8.
  float m = -3.4e38f;
#pragma unroll
  for (int q = 0; q < 8; ++q) m = fmaxf(m, e_f[(g * 8 + q) * 9 + h]);
  m = fmaxf(m, __shfl_xor(m, 8, 64));
  m = fmaxf(m, __shfl_xor(m, 16, 64));
  m = fmaxf(m, __shfl_xor(m, 32, 64));
  float ssum = 0.f;
#pragma unroll
  for (int q = 0; q < 8; ++q) ssum += __expf(e_f[(g * 8 + q) * 9 + h] - m);
  ssum += __shfl_xor(ssum, 8, 64);
  ssum += __shfl_xor(ssum, 16, 64);
  ssum += __shfl_xor(ssum, 32, 64);
  float rinv = 1.f / ssum;

  // alpha for own rows (e still in regs); consumed only by this wave's Phase C.
#pragma unroll
  for (int pp = 0; pp < 2; ++pp) {
    int n = w * 16 + g + 8 * pp;
    alpha_f[n * 8 + h] = __expf(er[pp] - m) * rinv;
  }

  // Phase C: y partials from register-held xj; alpha reads are wave-uniform
  // broadcasts — no barrier needed.
  float4 acc4[8];
#pragma unroll
  for (int hh = 0; hh < 8; ++hh) acc4[hh] = make_float4(0.f, 0.f, 0.f, 0.f);
#pragma unroll
  for (int i = 0; i < 16; ++i) {
    int n = w * 16 + i;
    float4 a0 = *(const float4*)(alpha_f + n * 8);
    float4 a1 = *(const float4*)(alpha_f + n * 8 + 4);
    float al[8] = {a0.x, a0.y, a0.z, a0.w, a1.x, a1.y, a1.z, a1.w};
    float4 x = xj[i];
#pragma unroll
    for (int hh = 0; hh < 8; ++hh) {
      acc4[hh].x += al[hh] * x.x;
      acc4[hh].y += al[hh] * x.y;
      acc4[hh].z += al[hh] * x.z;
      acc4[hh].w += al[hh] * x.w;
    }
  }
#pragma unroll
  for (int hh = 0; hh < 8; ++hh)
    *(float4*)(yp_f + (w * 8 + hh) * 260 + 4 * l) = acc4[hh];  // stride 260: epilogue reads conflict-free
  __syncthreads();  // barrier 2: yp complete

  // Epilogue: out[c] = elu(y[h(c)] . W[:,c]); k split across waves, float4 W loads,
  // 4-wave partials reduced via LDS.
  {
    const float* ypb = yp_f + g * 260;          // g == (4l)>>5: head of columns 4l..4l+3
    const float4* W4 = (const float4*)W;        // W4[k*64 + l] = W[k][4l..4l+3]
    float4 acc = make_float4(0.f, 0.f, 0.f, 0.f);
    int k0 = w * 64;
#pragma unroll 8
    for (int kk = 0; kk < 64; ++kk) {
      int k = k0 + kk;
      float yv = ypb[k] + ypb[2080 + k] + ypb[4160 + k] + ypb[6240 + k];
      float4 wv = W4[k * 64 + l];
      acc.x += yv * wv.x;
      acc.y += yv * wv.y;
      acc.z += yv * wv.z;
      acc.w += yv * wv.w;
    }
    *(float4*)(pp_f + w * 256 + 4 * l) = acc;
  }
  __syncthreads();  // barrier 3: partials complete

  {
    float s = pp_f[t] + pp_f[256 + t] + pp_f[512 + t] + pp_f[768 + t];
    out[(size_t)b * 256 + t] = s > 0.f ? s : (__expf(s) - 1.f);
  }
}

extern "C" void kernel_launch(void* const* d_in, const int* in_sizes, int n_in,
                              void* d_out, int out_size, void* d_ws, size_t ws_size,
                              hipStream_t stream) {
  const float* Xi = (const float*)d_in[0];
  const float* Xj = (const float*)d_in[1];
  const float* W = (const float*)d_in[2];
  const float* Watt = (const float*)d_in[3];
  float* out = (float*)d_out;
  float* V = (float*)d_ws;  // 2048 floats
  int B = in_sizes[0] / (NN * IND);
  precompute_v<<<(IND * NH + 255) / 256, 256, 0, stream>>>(W, Watt, V);
  gat_fused<<<B, 256, 0, stream>>>(Xi, Xj, W, V, out);
}

// Round 4
// 285.002 us; speedup vs baseline: 1.1426x; 1.0288x over previous
//
#include <hip/hip_runtime.h>

#define NN 64
#define IND 256
#define NH 8
#define OD 32

typedef __attribute__((ext_vector_type(8))) short bf16x8;
typedef __attribute__((ext_vector_type(4))) float f32x4;

__device__ __forceinline__ unsigned f2bf(float f) {
  unsigned u = __float_as_uint(f);
  return (u + (((u >> 16) & 1u) + 0x7fffu)) >> 16;  // RNE
}

// V[h][k] = sum_d W[k, h*32+d] * Watt[h, d]   (8 x 256)
__global__ __launch_bounds__(256) void precompute_v(
    const float* __restrict__ W, const float* __restrict__ Watt, float* __restrict__ V) {
  int tid = blockIdx.x * 256 + threadIdx.x;
  if (tid >= IND * NH) return;
  int h = tid >> 8, k = tid & 255;
  float acc = 0.f;
#pragma unroll
  for (int d = 0; d < OD; ++d) acc += W[k * 256 + h * OD + d] * Watt[h * OD + d];
  V[h * 256 + k] = acc;
}

// LDS layout (bytes):
//  [0,     33792)  s bf16 [64][264] (row = 132 words = 33 granules -> odd-granule
//                  stride: MFMA frag b128 reads uniform over bank-quads)
//                  overlay post-barrier-1: yp float [32][260]  (33280 B)
//  [33792, 38016)  v bf16 [8][264]  (4224 B)
//                  overlay post-barrier-1: alpha float [64][8] (2048 B)
//                  overlay post-barrier-2: pp float [4][256]   (4096 B)
//  [38016, 40320)  e float [64][9]  (2304 B; 9-stride kills 8-way conflict)
#define V_OFF 33792
#define E_OFF (V_OFF + 4224)
#define SMEM_BYTES (E_OFF + 2304)

// NOTE: no min-waves arg. Measured: (256,3)->84 VGPR cap, (256,4)->64 VGPR cap
// -> spill (WRITE_SIZE 62/122 MB). Plain bounds -> 108 VGPR, no spill; LDS=40448
// caps occupancy at 4 blocks/CU either way.
__global__ __launch_bounds__(256) void gat_fused(
    const float* __restrict__ Xi, const float* __restrict__ Xj,
    const float* __restrict__ W, const float* __restrict__ V,
    float* __restrict__ out) {
  __shared__ __align__(16) unsigned char smem[SMEM_BYTES];
  unsigned* s_pk = (unsigned*)smem;
  unsigned* v_pk = (unsigned*)(smem + V_OFF);
  float* e_f = (float*)(smem + E_OFF);
  float* alpha_f = (float*)(smem + V_OFF);  // overlay: valid after barrier 1 (v dead)
  float* pp_f = (float*)(smem + V_OFF);     // overlay: valid after barrier 3 (alpha dead)
  float* yp_f = (float*)smem;               // overlay: valid after barrier 1 (s dead)

  const int t = threadIdx.x;
  const int b = blockIdx.x;
  const int w = t >> 6, l = t & 63;
  const int g = l >> 3, h = l & 7;

  // wave w owns rows [16w, 16w+16) end-to-end
  const float4* Xi4 = (const float4*)Xi + (size_t)b * (NN * IND / 4) + w * 1024;
  const float4* Xj4 = (const float4*)Xj + (size_t)b * (NN * IND / 4) + w * 1024;

  // stage V into LDS as bf16 [8][264] — redundantly per wave (identical values),
  // keeps Phase B wave-local (no barrier before B).
  {
    const float4* V4 = (const float4*)V;
#pragma unroll
    for (int r = 0; r < 8; ++r) {
      float4 vv = V4[r * 64 + l];
      unsigned p0 = f2bf(vv.x) | (f2bf(vv.y) << 16);
      unsigned p1 = f2bf(vv.z) | (f2bf(vv.w) << 16);
      *(uint2*)(v_pk + r * 132 + 2 * l) = make_uint2(p0, p1);
    }
  }

  // Phase A: xj persistent in regs (64 VGPR); xi streamed in 2 chunks of 8.
  float4 xj[16];
#pragma unroll
  for (int i = 0; i < 16; ++i) xj[i] = Xj4[i * 64 + l];
#pragma unroll
  for (int c = 0; c < 2; ++c) {
    float4 xi[8];
#pragma unroll
    for (int i = 0; i < 8; ++i) xi[i] = Xi4[(c * 8 + i) * 64 + l];
#pragma unroll
    for (int i = 0; i < 8; ++i) {
      int r = c * 8 + i;
      float4 a = xj[r], ci = xi[i];
      unsigned p0 = f2bf(a.x + ci.x) | (f2bf(a.y + ci.y) << 16);
      unsigned p1 = f2bf(a.z + ci.z) | (f2bf(a.w + ci.w) << 16);
      *(uint2*)(s_pk + (w * 16 + r) * 132 + l * 2) = make_uint2(p0, p1);
    }
  }

  // Phase B (MFMA): e[16w..16w+16)[0..8) = s-rows . V^T via mfma_f32_16x16x32_bf16.
  // A-frag: lane(q=l>>4, r=l&15) = s[16w+r][32*step + 8q + j] (16B contiguous).
  // B-frag: same k-map from V row (r&7) (rows 8-15 clamped -> dup C cols, discarded).
  // Dot is invariant to the shared k-permutation; C layout is the m89-verified one.
  // Wave-local: reads only this wave's s-rows -> still no barrier before B.
  {
    const int r16 = l & 15, q = l >> 4;
    const unsigned* arow = s_pk + (w * 16 + r16) * 132;
    const unsigned* brow = v_pk + (r16 & 7) * 132;
    f32x4 acc = {0.f, 0.f, 0.f, 0.f};
#pragma unroll
    for (int step = 0; step < 8; ++step) {
      bf16x8 af = *(const bf16x8*)(arow + step * 16 + q * 4);
      bf16x8 bfv = *(const bf16x8*)(brow + step * 16 + q * 4);
      acc = __builtin_amdgcn_mfma_f32_16x16x32_bf16(af, bfv, acc, 0, 0, 0);
    }
    if (r16 < 8) {
#pragma unroll
      for (int j = 0; j < 4; ++j) {
        float ev = acc[j];
        ev = ev >= 0.f ? ev : 0.2f * ev;           // leakyReLU
        e_f[(w * 16 + q * 4 + j) * 9 + r16] = ev;  // row=(l>>4)*4+j, col=l&15 (m89)
      }
    }
  }
  __syncthreads();  // barrier 1: e complete; s and v globally dead past this point

  // softmax over n per h: redundantly per wave (butterfly over the 8 lane-groups).
  float m = -3.4e38f;
#pragma unroll
  for (int q = 0; q < 8; ++q) m = fmaxf(m, e_f[(g * 8 + q) * 9 + h]);
  m = fmaxf(m, __shfl_xor(m, 8, 64));
  m = fmaxf(m, __shfl_xor(m, 16, 64));
  m = fmaxf(m, __shfl_xor(m, 32, 64));
  float ssum = 0.f;
#pragma unroll
  for (int q = 0; q < 8; ++q) ssum += __expf(e_f[(g * 8 + q) * 9 + h] - m);
  ssum += __shfl_xor(ssum, 8, 64);
  ssum += __shfl_xor(ssum, 16, 64);
  ssum += __shfl_xor(ssum, 32, 64);
  float rinv = 1.f / ssum;

  // alpha for own rows; consumed only by this wave's Phase C (no barrier).
#pragma unroll
  for (int pp = 0; pp < 2; ++pp) {
    int n = w * 16 + g + 8 * pp;
    alpha_f[n * 8 + h] = __expf(e_f[n * 9 + h] - m) * rinv;
  }

  // Phase C: y partials from register-held xj; alpha reads wave-uniform broadcasts.
  float4 acc4[8];
#pragma unroll
  for (int hh = 0; hh < 8; ++hh) acc4[hh] = make_float4(0.f, 0.f, 0.f, 0.f);
#pragma unroll
  for (int i = 0; i < 16; ++i) {
    int n = w * 16 + i;
    float4 a0 = *(const float4*)(alpha_f + n * 8);
    float4 a1 = *(const float4*)(alpha_f + n * 8 + 4);
    float al[8] = {a0.x, a0.y, a0.z, a0.w, a1.x, a1.y, a1.z, a1.w};
    float4 x = xj[i];
#pragma unroll
    for (int hh = 0; hh < 8; ++hh) {
      acc4[hh].x += al[hh] * x.x;
      acc4[hh].y += al[hh] * x.y;
      acc4[hh].z += al[hh] * x.z;
      acc4[hh].w += al[hh] * x.w;
    }
  }
#pragma unroll
  for (int hh = 0; hh < 8; ++hh)
    *(float4*)(yp_f + (w * 8 + hh) * 260 + 4 * l) = acc4[hh];
  __syncthreads();  // barrier 2: yp complete

  // pre-reduce 32 partial rows -> 8 rows, fully vectorized (b128), in place.
  // Each (row,col4) chunk owned by exactly one thread: no hazards.
#pragma unroll
  for (int c = 0; c < 2; ++c) {
    int id = t + c * 256;                 // 0..511
    int row = id >> 6, col = (id & 63) * 4;
    float* p = yp_f + row * 260 + col;
    float4 s0 = *(float4*)p;
    float4 s1 = *(float4*)(p + 2080);
    float4 s2 = *(float4*)(p + 4160);
    float4 s3 = *(float4*)(p + 6240);
    s0.x += s1.x + s2.x + s3.x;
    s0.y += s1.y + s2.y + s3.y;
    s0.z += s1.z + s2.z + s3.z;
    s0.w += s1.w + s2.w + s3.w;
    *(float4*)p = s0;
  }
  __syncthreads();  // barrier 3: y (rows 0-7) complete

  // Epilogue: out[c] = elu(y[h(c)] . W[:,c]); k split across waves, y read as
  // float4 (16 b128 vs 256 b32), W float4 loads; 4-wave partials via LDS.
  {
    const float* ypb = yp_f + g * 260;    // g == (4l)>>5: head of columns 4l..4l+3
    const float4* W4 = (const float4*)W;  // W4[k*64 + l] = W[k][4l..4l+3]
    float4 acc = make_float4(0.f, 0.f, 0.f, 0.f);
    int k0 = w * 64;
#pragma unroll 8
    for (int kc = 0; kc < 16; ++kc) {
      int k = k0 + kc * 4;
      float4 yv = *(const float4*)(ypb + k);
      float4 w0 = W4[(k + 0) * 64 + l];
      float4 w1 = W4[(k + 1) * 64 + l];
      float4 w2 = W4[(k + 2) * 64 + l];
      float4 w3 = W4[(k + 3) * 64 + l];
      acc.x += yv.x * w0.x + yv.y * w1.x + yv.z * w2.x + yv.w * w3.x;
      acc.y += yv.x * w0.y + yv.y * w1.y + yv.z * w2.y + yv.w * w3.y;
      acc.z += yv.x * w0.z + yv.y * w1.z + yv.z * w2.z + yv.w * w3.z;
      acc.w += yv.x * w0.w + yv.y * w1.w + yv.z * w2.w + yv.w * w3.w;
    }
    *(float4*)(pp_f + w * 256 + 4 * l) = acc;
  }
  __syncthreads();  // barrier 4: partials complete

  {
    float s = pp_f[t] + pp_f[256 + t] + pp_f[512 + t] + pp_f[768 + t];
    out[(size_t)b * 256 + t] = s > 0.f ? s : (__expf(s) - 1.f);
  }
}

extern "C" void kernel_launch(void* const* d_in, const int* in_sizes, int n_in,
                              void* d_out, int out_size, void* d_ws, size_t ws_size,
                              hipStream_t stream) {
  const float* Xi = (const float*)d_in[0];
  const float* Xj = (const float*)d_in[1];
  const float* W = (const float*)d_in[2];
  const float* Watt = (const float*)d_in[3];
  float* out = (float*)d_out;
  float* V = (float*)d_ws;  // 2048 floats
  int B = in_sizes[0] / (NN * IND);
  precompute_v<<<(IND * NH + 255) / 256, 256, 0, stream>>>(W, Watt, V);
  gat_fused<<<B, 256, 0, stream>>>(Xi, Xj, W, V, out);
}